// Round 7
// baseline (1584.463 us; speedup 1.0000x reference)
//
#include <hip/hip_runtime.h>
#include <cstdint>
#include <cstddef>

// Problem constants (R,1,C) x, t, (K,C) A, (T,) bar_alpha
#define R_DIM 4096
#define K_DIM 16384
#define C_DIM 512
#define SPLITS 4                 // split over the 16384 k-dimension
#define BM 64                    // rows per workgroup
#define BK 128                   // k-tile
#define KRANGE (K_DIM / SPLITS)  // 4096
#define NTILES (KRANGE / BK)     // 32
#define GTILES (K_DIM / BK)      // 128 global tiles

typedef unsigned short us8 __attribute__((ext_vector_type(8)));
typedef float f32x4 __attribute__((ext_vector_type(4)));
typedef float f32x16 __attribute__((ext_vector_type(16)));
typedef __bf16 bfv8 __attribute__((ext_vector_type(8)));
typedef _Float16 f16x4 __attribute__((ext_vector_type(4)));

#define MFMA32(a, b, c) __builtin_amdgcn_mfma_f32_32x32x16_bf16((a), (b), (c), 0, 0, 0)
#define BC(v) __builtin_bit_cast(bfv8, (v))

__device__ __forceinline__ unsigned short f2bf(float v) {
    union { float f; unsigned u; } x; x.f = v;
    unsigned r = x.u + 0x7fffu + ((x.u >> 16) & 1u);  // RNE
    return (unsigned short)(r >> 16);
}
__device__ __forceinline__ float bf2f(unsigned short b) {
    union { unsigned u; float f; } x; x.u = ((unsigned)b) << 16;
    return x.f;
}

__device__ __forceinline__ void gload16(const char* g, char* l) {
    __builtin_amdgcn_global_load_lds(
        (const __attribute__((address_space(1))) void*)g,
        (__attribute__((address_space(3))) void*)l, 16, 0, 0);
}

// ---------------- workspace layout (bytes) — total == proven 109,314,048 ----------------
#define OFF_IMGA ((size_t)0)          // [GTILES][8][32768]  32 MB  Phase-A chunk images
#define OFF_IMGC ((size_t)33554432)   // [GTILES][8][32768]  32 MB  Phase-C chunk images
#define OFF_XH   ((size_t)67108864)   // [R][C] bf16 hi    4 MB
#define OFF_XL   ((size_t)71303168)   // [R][C] bf16 lo    4 MB
#define OFF_ASQ  ((size_t)75497472)   // [K] f32          64 KB
#define OFF_PM   ((size_t)75563008)   // [R][SPLITS] f32  64 KB used (128 KB slot)
#define OFF_PL   ((size_t)75694080)   // [R][SPLITS] f16  32 KB used (64 KB slot)
#define OFF_PO   ((size_t)75759616)   // [R][SPLITS][C] f16  16 MB used (32 MB slot)
#define WS_NEED  ((size_t)109314048)

// ---------------- LDS layout (bytes) ----------------
#define SM_BUF0 0        // staging buffer 0: 32 KB (hi 16K, lo 16K)
#define SM_BUF1 32768    // staging buffer 1
#define SM_U    65536    // u hi [64m][128k] bf16 swizzled  16 KB
#define SM_U2   81920    // u lo                            16 KB
#define SM_ROWL 98304    // float2[64] {sa, ce}            512 B
#define SM_MR   98816    // float[64] running max          256 B
#define SM_LR   99072    // float[64] running sum          256 B
#define SM_MAX  99328    // float[4][64] tile-max exchange   1 KB
#define SM_SUM  100352   // float[4][64] tile-sum exchange   1 KB
#define SM_TOT  101376

// ======================= prep kernels (unchanged formats) =======================

__global__ void k_splitx(const float* __restrict__ x, us8* __restrict__ xh, us8* __restrict__ xl) {
    int i = blockIdx.x * 256 + threadIdx.x;   // group of 8 elements
    if (i >= R_DIM * C_DIM / 8) return;
    const float4* x4 = (const float4*)x + (size_t)i * 2;
    float v[8];
    float4 a = x4[0], b = x4[1];
    v[0]=a.x; v[1]=a.y; v[2]=a.z; v[3]=a.w; v[4]=b.x; v[5]=b.y; v[6]=b.z; v[7]=b.w;
    us8 h, l;
#pragma unroll
    for (int j = 0; j < 8; ++j) {
        unsigned short hb = f2bf(v[j]);
        h[j] = hb;
        l[j] = f2bf(v[j] - bf2f(hb));
    }
    xh[i] = h; xl[i] = l;
}

// Phase-A chunk images: block=(gt,j). pos = kl*128 + ((cb ^ (kl&7))<<4)
__global__ __launch_bounds__(256) void k_imgA(const float* __restrict__ A, char* __restrict__ img) {
    int gt = blockIdx.x >> 3, j = blockIdx.x & 7;
    char* base = img + (size_t)blockIdx.x * 32768;
    int t = threadIdx.x;
#pragma unroll
    for (int it = 0; it < 4; ++it) {
        int p = t + it * 256;
        int kl = p >> 3, cb = p & 7;
        const float* src = A + (size_t)(gt * 128 + kl) * C_DIM + j * 64 + cb * 8;
        us8 h, l;
#pragma unroll
        for (int q = 0; q < 8; ++q) {
            float v = src[q];
            unsigned short hb = f2bf(v);
            h[q] = hb; l[q] = f2bf(v - bf2f(hb));
        }
        int pos = kl * 128 + ((cb ^ (kl & 7)) << 4);
        *(us8*)(base + pos) = h;
        *(us8*)(base + 16384 + pos) = l;
    }
}

// Phase-C chunk images (transposed): pos = cl*256 + ((kb ^ (cl&7))<<4)
__global__ __launch_bounds__(256) void k_imgC(const float* __restrict__ A, char* __restrict__ img) {
    int gt = blockIdx.x >> 3, j = blockIdx.x & 7;
    char* base = img + (size_t)blockIdx.x * 32768;
    int t = threadIdx.x;
#pragma unroll
    for (int it = 0; it < 4; ++it) {
        int p = t + it * 256;
        int cl = p & 63, kb = p >> 6;
        us8 h, l;
#pragma unroll
        for (int q = 0; q < 8; ++q) {
            float v = A[(size_t)(gt * 128 + kb * 8 + q) * C_DIM + j * 64 + cl];
            unsigned short hb = f2bf(v);
            h[q] = hb; l[q] = f2bf(v - bf2f(hb));
        }
        int pos = cl * 256 + ((kb ^ (cl & 7)) << 4);
        *(us8*)(base + pos) = h;
        *(us8*)(base + 16384 + pos) = l;
    }
}

__global__ void k_asq(const float* __restrict__ A, float* __restrict__ Asq) {
    int wid = threadIdx.x >> 6, lane = threadIdx.x & 63;
    int k = blockIdx.x * 4 + wid;
    const float4* a4 = (const float4*)(A + (size_t)k * C_DIM);
    float s = 0.f;
#pragma unroll
    for (int j = 0; j < 2; ++j) {
        float4 v = a4[lane * 2 + j];
        s += v.x * v.x + v.y * v.y + v.z * v.z + v.w * v.w;
    }
#pragma unroll
    for (int off = 32; off; off >>= 1) s += __shfl_xor(s, off);
    if (lane == 0) Asq[k] = s;
}

// ======================= fused flash-style kernel =======================
// grid = 256. Round-2's PROVEN working-set geometry (FETCH 522 MB):
//   split = (b>>1)&3, rb = (b>>3)*2 + (b&1)
// Under XCD = b%8: XCD v hosts ONLY split v>>1 (one img stream, 32 sharers)
// and 32 stride-2 row-slabs of 64 rows = 2048 rows -> x/XCD = 4 MB (L2-fit).
// 8 waves: Phase A/B (wm = wid>>2 in {0,1}, wk = wid&3): one 32x32 S-tile each.
// Phase C (wm, wc = (wid>>1)&1, wg = wid&1): tile (m=wm*32, c=j*64+wc*32),
// k-split halves (wg) merged once per block via LDS at the epilogue.
// 32x32x16 MFMA: A/B row/col = l&31, k-slot = (l>>5)*8+q; D: col=l&31,
// row = (reg&3)+8*(reg>>2)+4*(l>>5).
__global__ __launch_bounds__(512, 2) void k_fused(
    const char* __restrict__ imgA, const char* __restrict__ imgC,
    const unsigned short* __restrict__ xh, const unsigned short* __restrict__ xl,
    const float* __restrict__ Asq, const int* __restrict__ tarr,
    const float* __restrict__ bar_alpha,
    _Float16* __restrict__ pO, float* __restrict__ pM, _Float16* __restrict__ pL)
{
    extern __shared__ char smem[];
    const int tid = threadIdx.x;
    const int lane = tid & 63, wid = tid >> 6;
    const int wm = wid >> 2, wk = wid & 3;
    const int wc = wk >> 1, wg = wk & 1;
    const int l31 = lane & 31, hl = lane >> 5;
    const int b = blockIdx.x;
    const int split = (b >> 1) & 3;
    const int rbase = ((b >> 3) * 2 + (b & 1)) * BM;

    float2* rowl = (float2*)(smem + SM_ROWL);
    float* MrL = (float*)(smem + SM_MR);
    float* LrL = (float*)(smem + SM_LR);
    float* smax = (float*)(smem + SM_MAX);
    float* ssum = (float*)(smem + SM_SUM);

    if (tid < 64) {
        float ba = bar_alpha[tarr[rbase + tid]];
        float sa = sqrtf(ba);
        float ce = 1.4426950408889634f / (1.0f - ba);
        rowl[tid] = make_float2(sa, ce);
        MrL[tid] = -1e30f;
        LrL[tid] = 0.f;
    }
    const int stg = tid * 16;
    {   // stage A(tile0, chunk0) into BUF0
        const char* s = imgA + (size_t)(split * NTILES) * 8 * 32768 + stg;
        char* d = smem + SM_BUF0 + stg;
#pragma unroll
        for (int i = 0; i < 4; ++i) gload16(s + i * 8192, d + i * 8192);
    }
    __syncthreads();
    int cur = 0;

    f32x16 of[8];
#pragma unroll
    for (int j = 0; j < 8; ++j)
#pragma unroll
        for (int r = 0; r < 16; ++r) of[j][r] = 0.f;

    for (int kt = 0; kt < NTILES; ++kt) {
        const int gt = split * NTILES + kt;
        const int kbase = gt * BK;

        f32x16 sf;
#pragma unroll
        for (int r = 0; r < 16; ++r) sf[r] = 0.f;

        // ---------- Phase A: S[64m][128k] over c, 8 chunks of 64 ----------
#pragma unroll
        for (int j = 0; j < 8; ++j) {
            {   // stage next chunk (A j+1, or C 0 when j==7)
                const char* s = (j < 7) ? imgA + ((size_t)gt * 8 + j + 1) * 32768
                                        : imgC + ((size_t)gt * 8 + 0) * 32768;
                char* d = smem + (cur ? SM_BUF0 : SM_BUF1) + stg;
#pragma unroll
                for (int i = 0; i < 4; ++i) gload16(s + stg + i * 8192, d + i * 8192);
            }
            const char* B = smem + (cur ? SM_BUF1 : SM_BUF0);
#pragma unroll
            for (int cs = 0; cs < 4; ++cs) {
                int xoff = (rbase + wm * 32 + l31) * C_DIM + j * 64 + cs * 16 + hl * 8;
                us8 xh8 = *(const us8*)(xh + xoff);
                us8 xl8 = *(const us8*)(xl + xoff);
                int kl = wk * 32 + l31;
                int cb = cs * 2 + hl;
                int byte = kl * 128 + ((cb ^ (kl & 7)) << 4);
                bfv8 qh = *(const bfv8*)(B + byte);
                bfv8 ql = *(const bfv8*)(B + 16384 + byte);
                sf = MFMA32(BC(xh8), qh, sf);
                sf = MFMA32(BC(xh8), ql, sf);
                sf = MFMA32(BC(xl8), qh, sf);
            }
            __syncthreads();
            cur ^= 1;
        }

        // ---------- Phase B: online softmax ----------
        float asq = Asq[kbase + wk * 32 + l31];
        float g[16], mx[16], Mn[16];
#pragma unroll
        for (int r = 0; r < 16; ++r) {
            int ml = wm * 32 + (r & 3) + 8 * (r >> 2) + 4 * hl;
            float sa = rowl[ml].x;
            g[r] = sa * (sf[r] - 0.5f * sa * asq);
            mx[r] = g[r];
        }
#pragma unroll
        for (int off = 1; off < 32; off <<= 1)
#pragma unroll
            for (int r = 0; r < 16; ++r) mx[r] = fmaxf(mx[r], __shfl_xor(mx[r], off));
        if (l31 == 0) {
#pragma unroll
            for (int r = 0; r < 16; ++r)
                smax[wk * 64 + wm * 32 + (r & 3) + 8 * (r >> 2) + 4 * hl] = mx[r];
        }
        __syncthreads();
        float ts[16];
#pragma unroll
        for (int r = 0; r < 16; ++r) {
            int ml = wm * 32 + (r & 3) + 8 * (r >> 2) + 4 * hl;
            float tm = fmaxf(fmaxf(smax[ml], smax[64 + ml]),
                             fmaxf(smax[128 + ml], smax[192 + ml]));
            Mn[r] = fmaxf(MrL[ml], tm);
            float u = exp2f((g[r] - Mn[r]) * rowl[ml].y);
            ts[r] = u;
            unsigned short uh = f2bf(u);
            unsigned short ul = f2bf(u - bf2f(uh));
            int k = wk * 32 + l31;
            int byte = ml * 256 + (((k >> 3) ^ (ml & 7)) << 4) + (k & 7) * 2;
            *(unsigned short*)(smem + SM_U + byte) = uh;
            *(unsigned short*)(smem + SM_U2 + byte) = ul;
        }
#pragma unroll
        for (int off = 1; off < 32; off <<= 1)
#pragma unroll
            for (int r = 0; r < 16; ++r) ts[r] += __shfl_xor(ts[r], off);
        if (l31 == 0) {
#pragma unroll
            for (int r = 0; r < 16; ++r)
                ssum[wk * 64 + wm * 32 + (r & 3) + 8 * (r >> 2) + 4 * hl] = ts[r];
        }
        __syncthreads();   // U + ssum ready
        float al[16];
#pragma unroll
        for (int r = 0; r < 16; ++r) {
            int ml = wm * 32 + (r & 3) + 8 * (r >> 2) + 4 * hl;
            al[r] = exp2f((MrL[ml] - Mn[r]) * rowl[ml].y);
        }
#pragma unroll
        for (int j = 0; j < 8; ++j)
#pragma unroll
            for (int r = 0; r < 16; ++r) of[j][r] *= al[r];
        bfv8 uH[4], uL[4];
#pragma unroll
        for (int ks = 0; ks < 4; ++ks) {
            int m2 = wm * 32 + l31;
            int kb = wg * 8 + ks * 2 + hl;
            int byte = m2 * 256 + ((kb ^ (m2 & 7)) << 4);
            uH[ks] = *(const bfv8*)(smem + SM_U + byte);
            uL[ks] = *(const bfv8*)(smem + SM_U2 + byte);
        }
        __syncthreads();   // all MrL reads done
        if (wk == 0 && l31 == 0) {
#pragma unroll
            for (int r = 0; r < 16; ++r) {
                int ml = wm * 32 + (r & 3) + 8 * (r >> 2) + 4 * hl;
                float s4 = (ssum[ml] + ssum[64 + ml]) + (ssum[128 + ml] + ssum[192 + ml]);
                LrL[ml] = LrL[ml] * al[r] + s4;
                MrL[ml] = Mn[r];
            }
        }

        // ---------- Phase C: O[64m][512c] += u * A_tile, 8 chunks of 64 c ----------
#pragma unroll
        for (int j = 0; j < 8; ++j) {
            if (j < 7) {
                const char* s = imgC + ((size_t)gt * 8 + j + 1) * 32768;
                char* d = smem + (cur ? SM_BUF0 : SM_BUF1) + stg;
#pragma unroll
                for (int i = 0; i < 4; ++i) gload16(s + stg + i * 8192, d + i * 8192);
            } else if (kt < NTILES - 1) {
                const char* s = imgA + ((size_t)(gt + 1) * 8 + 0) * 32768;
                char* d = smem + (cur ? SM_BUF0 : SM_BUF1) + stg;
#pragma unroll
                for (int i = 0; i < 4; ++i) gload16(s + stg + i * 8192, d + i * 8192);
            }
            const char* B = smem + (cur ? SM_BUF1 : SM_BUF0);
#pragma unroll
            for (int ks = 0; ks < 4; ++ks) {
                int cl = wc * 32 + l31;
                int kb = wg * 8 + ks * 2 + hl;
                int byte = cl * 256 + ((kb ^ (cl & 7)) << 4);
                bfv8 qh = *(const bfv8*)(B + byte);
                bfv8 ql = *(const bfv8*)(B + 16384 + byte);
                of[j] = MFMA32(uH[ks], qh, of[j]);
                of[j] = MFMA32(uH[ks], ql, of[j]);
                of[j] = MFMA32(uL[ks], qh, of[j]);
            }
            __syncthreads();
            cur ^= 1;
        }
    }

    // ---------- epilogue: merge wg k-halves via LDS, then write partials ----------
    float* mbuf = (float*)(smem + SM_BUF0);
#pragma unroll
    for (int j = 0; j < 8; ++j) {
        if (wg == 1) {
#pragma unroll
            for (int r = 0; r < 16; ++r)
                mbuf[((wm * 2 + wc) * 64 + lane) * 16 + r] = of[j][r];
        }
        __syncthreads();
        if (wg == 0) {
#pragma unroll
            for (int r = 0; r < 16; ++r)
                of[j][r] += mbuf[((wm * 2 + wc) * 64 + lane) * 16 + r];
        }
        __syncthreads();
    }
    if (wg == 0) {
#pragma unroll
        for (int j = 0; j < 8; ++j)
#pragma unroll
            for (int r = 0; r < 16; ++r) {
                int gm = rbase + wm * 32 + (r & 3) + 8 * (r >> 2) + 4 * hl;
                int cg = j * 64 + wc * 32 + l31;
                pO[((size_t)gm * SPLITS + split) * C_DIM + cg] = (_Float16)of[j][r];
            }
    }
    if (tid < 64) {
        pM[(rbase + tid) * SPLITS + split] = MrL[tid];
        pL[(rbase + tid) * SPLITS + split] = (_Float16)LrL[tid];
    }
}

// ======================= split-K combine =======================
__global__ void k_combine(const _Float16* __restrict__ pO, const float* __restrict__ pM,
                          const _Float16* __restrict__ pL, const int* __restrict__ tarr,
                          const float* __restrict__ bar_alpha, float* __restrict__ out) {
    int r = blockIdx.x;
    int tid = threadIdx.x;   // 128 threads, 4 c's each
    float ba = bar_alpha[tarr[r]];
    float ce = 1.4426950408889634f / (1.0f - ba);
    float Ms[SPLITS], Ls[SPLITS];
    float M = -1e30f;
#pragma unroll
    for (int s = 0; s < SPLITS; ++s) {
        Ms[s] = pM[r * SPLITS + s];
        Ls[s] = (float)pL[r * SPLITS + s];
        M = fmaxf(M, Ms[s]);
    }
    float es[SPLITS], L = 0.f;
#pragma unroll
    for (int s = 0; s < SPLITS; ++s) { es[s] = exp2f((Ms[s] - M) * ce); L += Ls[s] * es[s]; }
    float invL = 1.0f / L;
    f32x4 acc = (f32x4){0.f, 0.f, 0.f, 0.f};
#pragma unroll
    for (int s = 0; s < SPLITS; ++s) {
        f16x4 v = *(const f16x4*)(pO + ((size_t)r * SPLITS + s) * C_DIM + tid * 4);
        f32x4 vf = (f32x4){(float)v[0], (float)v[1], (float)v[2], (float)v[3]};
        acc += vf * es[s];
    }
    acc *= invL;
    *(f32x4*)(out + (size_t)r * C_DIM + tid * 4) = acc;
}

// ======================= launch =======================
extern "C" void kernel_launch(void* const* d_in, const int* in_sizes, int n_in,
                              void* d_out, int out_size, void* d_ws, size_t ws_size,
                              hipStream_t stream) {
    const float* x = (const float*)d_in[0];
    const int* t = (const int*)d_in[1];
    const float* A = (const float*)d_in[2];
    const float* bar_alpha = (const float*)d_in[3];
    float* out = (float*)d_out;
    char* ws = (char*)d_ws;
    if (ws_size < WS_NEED) return;

    char* imgA = ws + OFF_IMGA;
    char* imgC = ws + OFF_IMGC;
    unsigned short* Xh = (unsigned short*)(ws + OFF_XH);
    unsigned short* Xl = (unsigned short*)(ws + OFF_XL);
    float* Asq = (float*)(ws + OFF_ASQ);
    float* pM = (float*)(ws + OFF_PM);
    _Float16* pL = (_Float16*)(ws + OFF_PL);
    _Float16* pO = (_Float16*)(ws + OFF_PO);

    (void)hipFuncSetAttribute((const void*)k_fused,
                              hipFuncAttributeMaxDynamicSharedMemorySize, SM_TOT);

    k_splitx<<<(R_DIM * C_DIM / 8) / 256, 256, 0, stream>>>(x, (us8*)Xh, (us8*)Xl);
    k_imgA<<<GTILES * 8, 256, 0, stream>>>(A, imgA);
    k_imgC<<<GTILES * 8, 256, 0, stream>>>(A, imgC);
    k_asq<<<K_DIM / 4, 256, 0, stream>>>(A, Asq);
    k_fused<<<256, 512, SM_TOT, stream>>>(imgA, imgC, Xh, Xl, Asq, t, bar_alpha,
                                          pO, pM, pL);
    k_combine<<<R_DIM, 128, 0, stream>>>(pO, pM, pL, t, bar_alpha, out);
}

// Round 8
// 679.549 us; speedup vs baseline: 2.3316x; 2.3316x over previous
//
#include <hip/hip_runtime.h>
#include <cstdint>
#include <cstddef>

// Problem constants (R,1,C) x, t, (K,C) A, (T,) bar_alpha
#define R_DIM 4096
#define K_DIM 16384
#define C_DIM 512
#define SPLITS 4                 // split over the 16384 k-dimension
#define BM 64                    // rows per workgroup
#define BK 128                   // k-tile
#define KRANGE (K_DIM / SPLITS)  // 4096
#define NTILES (KRANGE / BK)     // 32
#define GTILES (K_DIM / BK)      // 128 global tiles

typedef unsigned short us8 __attribute__((ext_vector_type(8)));
typedef float f32x4 __attribute__((ext_vector_type(4)));
typedef __bf16 bfv8 __attribute__((ext_vector_type(8)));

#define MFMA16(a, b, c) __builtin_amdgcn_mfma_f32_16x16x32_bf16((a), (b), (c), 0, 0, 0)
#define BC(v) __builtin_bit_cast(bfv8, (v))

__device__ __forceinline__ unsigned short f2bf(float v) {
    union { float f; unsigned u; } x; x.f = v;
    unsigned r = x.u + 0x7fffu + ((x.u >> 16) & 1u);  // RNE
    return (unsigned short)(r >> 16);
}
__device__ __forceinline__ float bf2f(unsigned short b) {
    union { unsigned u; float f; } x; x.u = ((unsigned)b) << 16;
    return x.f;
}

// async global->LDS, 16B per lane.
__device__ __forceinline__ void gload16(const char* g, char* l) {
    __builtin_amdgcn_global_load_lds(
        (const __attribute__((address_space(1))) void*)g,
        (__attribute__((address_space(3))) void*)l, 16, 0, 0);
}

// ---------------- workspace layout (bytes) ----------------
#define OFF_IMGA ((size_t)0)          // [GTILES][8][32768]  32 MB   [128k][64c] images
#define OFF_IMGC ((size_t)33554432)   // [GTILES][8][32768]  32 MB   [64c][128k] images
#define OFF_XH   ((size_t)67108864)   // [R][C] bf16 hi    4 MB
#define OFF_XL   ((size_t)71303168)   // [R][C] bf16 lo    4 MB
#define OFF_ASQ  ((size_t)75497472)   // [K] f32          64 KB
#define OFF_ROWP ((size_t)75563008)   // [R] float4       64 KB  {sa, 0.5*sa*sa, inv*log2e, inv}
#define OFF_PO   ((size_t)75628544)   // [R][SPLITS][C] f32  32 MB
#define OFF_PM   ((size_t)109182976)  // [R][SPLITS] f32  64 KB
#define OFF_PL   ((size_t)109248512)  // [R][SPLITS] f32  64 KB
#define WS_NEED  ((size_t)109314048)

// ---------------- LDS layout (bytes) ----------------
#define SM_BUF0 0        // staging buffer 0: 32 KB (hi 16K, lo 16K)
#define SM_BUF1 32768    // staging buffer 1: 32 KB
#define SM_U    65536    // u hi [64m][128k] bf16 swizzled  16 KB
#define SM_U2   81920    // u lo                            16 KB
#define SM_MX   98304    // float[2][64] tile-max exchange
#define SM_SM   98816    // float[2][64] tile-sum exchange
#define SM_TOT  99328

// ======================= prep kernels =======================

__global__ void k_rows(const int* __restrict__ t, const float* __restrict__ bar_alpha,
                       float4* __restrict__ rowp) {
    int r = blockIdx.x * 256 + threadIdx.x;
    if (r >= R_DIM) return;
    float ba = bar_alpha[t[r]];
    float sa = sqrtf(ba);
    float inv = 1.0f / (1.0f - ba);
    rowp[r] = make_float4(sa, 0.5f * sa * sa, inv * 1.4426950408889634f, inv);
}

__global__ void k_splitx(const float* __restrict__ x, us8* __restrict__ xh, us8* __restrict__ xl) {
    int i = blockIdx.x * 256 + threadIdx.x;   // group of 8 elements
    if (i >= R_DIM * C_DIM / 8) return;
    const float4* x4 = (const float4*)x + (size_t)i * 2;
    float v[8];
    float4 a = x4[0], b = x4[1];
    v[0]=a.x; v[1]=a.y; v[2]=a.z; v[3]=a.w; v[4]=b.x; v[5]=b.y; v[6]=b.z; v[7]=b.w;
    us8 h, l;
#pragma unroll
    for (int j = 0; j < 8; ++j) {
        unsigned short hb = f2bf(v[j]);
        h[j] = hb;
        l[j] = f2bf(v[j] - bf2f(hb));
    }
    xh[i] = h; xl[i] = l;
}

// Phase-A chunk images: block = (gt, j). pos = kl*128 + ((cb*16) ^ ((kl&7)<<4))
__global__ __launch_bounds__(256) void k_imgA(const float* __restrict__ A, char* __restrict__ img) {
    int gt = blockIdx.x >> 3, j = blockIdx.x & 7;
    char* base = img + (size_t)blockIdx.x * 32768;
    int t = threadIdx.x;
#pragma unroll
    for (int it = 0; it < 4; ++it) {
        int p = t + it * 256;
        int kl = p >> 3, cb = p & 7;
        const float* src = A + (size_t)(gt * 128 + kl) * C_DIM + j * 64 + cb * 8;
        us8 h, l;
#pragma unroll
        for (int q = 0; q < 8; ++q) {
            float v = src[q];
            unsigned short hb = f2bf(v);
            h[q] = hb; l[q] = f2bf(v - bf2f(hb));
        }
        int pos = kl * 128 + ((cb * 16) ^ ((kl & 7) << 4));
        *(us8*)(base + pos) = h;
        *(us8*)(base + 16384 + pos) = l;
    }
}

// Phase-C chunk images (transposed): pos = cl*256 + ((kb*16) ^ ((cl&7)<<4))
__global__ __launch_bounds__(256) void k_imgC(const float* __restrict__ A, char* __restrict__ img) {
    int gt = blockIdx.x >> 3, j = blockIdx.x & 7;
    char* base = img + (size_t)blockIdx.x * 32768;
    int t = threadIdx.x;
#pragma unroll
    for (int it = 0; it < 4; ++it) {
        int p = t + it * 256;
        int cl = p & 63, kb = p >> 6;
        us8 h, l;
#pragma unroll
        for (int q = 0; q < 8; ++q) {
            float v = A[(size_t)(gt * 128 + kb * 8 + q) * C_DIM + j * 64 + cl];
            unsigned short hb = f2bf(v);
            h[q] = hb; l[q] = f2bf(v - bf2f(hb));
        }
        int pos = cl * 256 + ((kb * 16) ^ ((cl & 7) << 4));
        *(us8*)(base + pos) = h;
        *(us8*)(base + 16384 + pos) = l;
    }
}

__global__ void k_asq(const float* __restrict__ A, float* __restrict__ Asq) {
    int wid = threadIdx.x >> 6, lane = threadIdx.x & 63;
    int k = blockIdx.x * 4 + wid;
    const float4* a4 = (const float4*)(A + (size_t)k * C_DIM);
    float s = 0.f;
#pragma unroll
    for (int j = 0; j < 2; ++j) {
        float4 v = a4[lane * 2 + j];
        s += v.x * v.x + v.y * v.y + v.z * v.z + v.w * v.w;
    }
#pragma unroll
    for (int off = 32; off; off >>= 1) s += __shfl_xor(s, off);
    if (lane == 0) Asq[k] = s;
}

// ======================= fused flash-style kernel =======================
// BYTE-EXACT round-2 structure (proven: 761 us, FETCH 522 MB) with ONE edit:
// Phase C is 2-term: O += (uh+ul)*Ah  (Al dropped in GEMM2 only; GEMM1 keeps
// all 3 split terms for argmax stability). C-chunk staging is hi-only (16 KB).
// grid = 64 rowblocks * 4 splits (blockIdx = rb*4+split), 512 threads, 8 waves
// (wr = wid>>1 row-group, wc = wid&1).
__global__ __launch_bounds__(512, 2) void k_fused(
    const char* __restrict__ imgA, const char* __restrict__ imgC,
    const unsigned short* __restrict__ xh, const unsigned short* __restrict__ xl,
    const float* __restrict__ Asq, const float4* __restrict__ rowp,
    float* __restrict__ pO, float* __restrict__ pM, float* __restrict__ pL)
{
    extern __shared__ char smem[];
    const int tid = threadIdx.x;
    const int lane = tid & 63, wid = tid >> 6;
    const int wr = wid >> 1, wc = wid & 1;
    const int l15 = lane & 15, l4 = lane >> 4;
    const int rb = (blockIdx.x >> 2) * BM;
    const int split = blockIdx.x & (SPLITS - 1);

    float sa[4], hb[4], ce[4];
#pragma unroll
    for (int q = 0; q < 4; ++q) {
        float4 p = rowp[rb + wr * 16 + l4 * 4 + q];
        sa[q] = p.x; hb[q] = p.y; ce[q] = p.z;
    }
    float Mr[4], Lr[4];
#pragma unroll
    for (int q = 0; q < 4; ++q) { Mr[q] = -1e30f; Lr[q] = 0.f; }
    f32x4 of[8][2];   // [c-chunk j][c-frag f]
#pragma unroll
    for (int a = 0; a < 8; ++a)
#pragma unroll
        for (int b = 0; b < 2; ++b) of[a][b] = (f32x4){0.f, 0.f, 0.f, 0.f};

    const int xrow = (rb + wr * 16 + l15) * C_DIM;
    const int stg = tid * 16;

    // prologue: stage A(tile 0, chunk 0) into BUF0
    {
        const char* s = imgA + (size_t)(split * NTILES) * 8 * 32768 + stg;
        char* d = smem + SM_BUF0 + stg;
#pragma unroll
        for (int i = 0; i < 4; ++i) gload16(s + i * 8192, d + i * 8192);
    }
    __syncthreads();
    int cur = 0;

    for (int kt = 0; kt < NTILES; ++kt) {
        const int gt = split * NTILES + kt;
        const int kbase = gt * BK;
        f32x4 sf[4];
#pragma unroll
        for (int f = 0; f < 4; ++f) sf[f] = (f32x4){0.f, 0.f, 0.f, 0.f};

        // ---------- Phase A: S[64m][128k] = (xh+xl)(Ah+Al)^T, 8 chunks of 64 c ----------
        us8 xbh[2][2], xbl[2][2];
#pragma unroll
        for (int cs = 0; cs < 2; ++cs) {   // cold load for chunk 0
            int off = xrow + 0 * 64 + cs * 32 + l4 * 8;
            xbh[0][cs] = *(const us8*)(xh + off);
            xbl[0][cs] = *(const us8*)(xl + off);
        }
#pragma unroll
        for (int j = 0; j < 8; ++j) {
            // stage next chunk (A j+1 hi+lo, or C 0 hi-only when j==7) into buf^1
            {
                char* d = smem + (cur ? SM_BUF0 : SM_BUF1) + stg;
                if (j < 7) {
                    const char* s = imgA + ((size_t)gt * 8 + j + 1) * 32768;
#pragma unroll
                    for (int i = 0; i < 4; ++i) gload16(s + stg + i * 8192, d + i * 8192);
                } else {
                    const char* s = imgC + ((size_t)gt * 8 + 0) * 32768;
#pragma unroll
                    for (int i = 0; i < 2; ++i) gload16(s + stg + i * 8192, d + i * 8192);
                }
            }
            // prefetch next chunk's x frags (landed by this chunk's barrier)
            if (j < 7) {
#pragma unroll
                for (int cs = 0; cs < 2; ++cs) {
                    int off = xrow + (j + 1) * 64 + cs * 32 + l4 * 8;
                    xbh[(j + 1) & 1][cs] = *(const us8*)(xh + off);
                    xbl[(j + 1) & 1][cs] = *(const us8*)(xl + off);
                }
            }
            // MFMA on current buffer
            const char* B = smem + (cur ? SM_BUF1 : SM_BUF0);
#pragma unroll
            for (int cs = 0; cs < 2; ++cs) {
#pragma unroll
                for (int f = 0; f < 4; ++f) {
                    int row = wc * 64 + f * 16 + l15;              // k-index in tile
                    int byte = row * 128 + ((cs * 64 + l4 * 16) ^ ((row & 7) << 4));
                    bfv8 qh = *(const bfv8*)(B + byte);
                    bfv8 ql = *(const bfv8*)(B + 16384 + byte);
                    sf[f] = MFMA16(BC(xbh[j & 1][cs]), qh, sf[f]);
                    sf[f] = MFMA16(BC(xbh[j & 1][cs]), ql, sf[f]);
                    sf[f] = MFMA16(BC(xbl[j & 1][cs]), qh, sf[f]);
                }
            }
            __syncthreads();
            cur ^= 1;
        }

        // ---------- Phase B: online softmax ----------
        float g[4][4];
#pragma unroll
        for (int f = 0; f < 4; ++f) {
            float asq = Asq[kbase + wc * 64 + f * 16 + l15];
#pragma unroll
            for (int q = 0; q < 4; ++q) g[f][q] = sa[q] * sf[f][q] - hb[q] * asq;
        }
        float tmax[4];
#pragma unroll
        for (int q = 0; q < 4; ++q)
            tmax[q] = fmaxf(fmaxf(g[0][q], g[1][q]), fmaxf(g[2][q], g[3][q]));
#pragma unroll
        for (int off = 1; off < 16; off <<= 1)
#pragma unroll
            for (int q = 0; q < 4; ++q) tmax[q] = fmaxf(tmax[q], __shfl_xor(tmax[q], off));
        float* smax = (float*)(smem + SM_MX);
        if (l15 == 0) {
#pragma unroll
            for (int q = 0; q < 4; ++q) smax[wc * 64 + wr * 16 + l4 * 4 + q] = tmax[q];
        }
        __syncthreads();
        float Mn[4], al[4];
#pragma unroll
        for (int q = 0; q < 4; ++q) {
            float other = smax[(wc ^ 1) * 64 + wr * 16 + l4 * 4 + q];
            float tm = fmaxf(tmax[q], other);
            Mn[q] = fmaxf(Mr[q], tm);
            al[q] = exp2f((Mr[q] - Mn[q]) * ce[q]);
        }
        float u[4][4], tsum[4] = {0.f, 0.f, 0.f, 0.f};
#pragma unroll
        for (int f = 0; f < 4; ++f)
#pragma unroll
            for (int q = 0; q < 4; ++q) {
                u[f][q] = exp2f((g[f][q] - Mn[q]) * ce[q]);
                tsum[q] += u[f][q];
            }
#pragma unroll
        for (int off = 1; off < 16; off <<= 1)
#pragma unroll
            for (int q = 0; q < 4; ++q) tsum[q] += __shfl_xor(tsum[q], off);
        float* ssum = (float*)(smem + SM_SM);
        if (l15 == 0) {
#pragma unroll
            for (int q = 0; q < 4; ++q) ssum[wc * 64 + wr * 16 + l4 * 4 + q] = tsum[q];
        }
        // write u (bf16 hi/lo) to LDS for GEMM2 A-operand
#pragma unroll
        for (int f = 0; f < 4; ++f)
#pragma unroll
            for (int q = 0; q < 4; ++q) {
                int m_loc = wr * 16 + l4 * 4 + q;
                int k_loc = wc * 64 + f * 16 + l15;
                int byte = (m_loc * 256 + k_loc * 2) ^ ((m_loc & 7) << 4);
                unsigned short uh = f2bf(u[f][q]);
                *(unsigned short*)(smem + SM_U + byte) = uh;
                *(unsigned short*)(smem + SM_U2 + byte) = f2bf(u[f][q] - bf2f(uh));
            }
        __syncthreads();
#pragma unroll
        for (int q = 0; q < 4; ++q) {
            float others = ssum[(wc ^ 1) * 64 + wr * 16 + l4 * 4 + q];
            Lr[q] = Lr[q] * al[q] + tsum[q] + others;
            Mr[q] = Mn[q];
        }
#pragma unroll
        for (int a = 0; a < 8; ++a)
#pragma unroll
            for (int b = 0; b < 2; ++b)
#pragma unroll
                for (int q = 0; q < 4; ++q) of[a][b][q] *= al[q];

        // ---------- Phase C: O[64m][512c] += (uh+ul) * Ah_tile, 8 chunks of 64 c ----------
        us8 uhf[4], ulf[4];
#pragma unroll
        for (int ks = 0; ks < 4; ++ks) {
            int m_loc = wr * 16 + l15;
            int byte = (m_loc * 256 + ks * 64 + l4 * 16) ^ ((m_loc & 7) << 4);
            uhf[ks] = *(const us8*)(smem + SM_U + byte);
            ulf[ks] = *(const us8*)(smem + SM_U2 + byte);
        }
#pragma unroll
        for (int j = 0; j < 8; ++j) {
            // stage next chunk (C j+1 hi-only, or next tile's A 0 hi+lo)
            if (j < 7) {
                const char* s = imgC + ((size_t)gt * 8 + j + 1) * 32768;
                char* d = smem + (cur ? SM_BUF0 : SM_BUF1) + stg;
#pragma unroll
                for (int i = 0; i < 2; ++i) gload16(s + stg + i * 8192, d + i * 8192);
            } else if (kt < NTILES - 1) {
                const char* s = imgA + ((size_t)(gt + 1) * 8 + 0) * 32768;
                char* d = smem + (cur ? SM_BUF0 : SM_BUF1) + stg;
#pragma unroll
                for (int i = 0; i < 4; ++i) gload16(s + stg + i * 8192, d + i * 8192);
            }
            const char* B = smem + (cur ? SM_BUF1 : SM_BUF0);
#pragma unroll
            for (int f = 0; f < 2; ++f) {
                int cl = wc * 32 + f * 16 + l15;                   // c-row in chunk
#pragma unroll
                for (int ks = 0; ks < 4; ++ks) {
                    int byte = cl * 256 + ((ks * 64 + l4 * 16) ^ ((cl & 7) << 4));
                    bfv8 qh = *(const bfv8*)(B + byte);
                    of[j][f] = MFMA16(BC(uhf[ks]), qh, of[j][f]);
                    of[j][f] = MFMA16(BC(ulf[ks]), qh, of[j][f]);
                }
            }
            __syncthreads();
            cur ^= 1;
        }
    }

    // ---------- write split partials ----------
#pragma unroll
    for (int j = 0; j < 8; ++j)
#pragma unroll
        for (int f = 0; f < 2; ++f)
#pragma unroll
            for (int q = 0; q < 4; ++q) {
                int gm = rb + wr * 16 + l4 * 4 + q;
                int cg = j * 64 + wc * 32 + f * 16 + l15;
                pO[((size_t)gm * SPLITS + split) * C_DIM + cg] = of[j][f][q];
            }
    if (wc == 0 && l15 == 0) {
#pragma unroll
        for (int q = 0; q < 4; ++q) {
            int gm = rb + wr * 16 + l4 * 4 + q;
            pM[gm * SPLITS + split] = Mr[q];
            pL[gm * SPLITS + split] = Lr[q];
        }
    }
}

// ======================= split-K combine =======================
__global__ void k_combine(const float* __restrict__ pO, const float* __restrict__ pM,
                          const float* __restrict__ pL, const float4* __restrict__ rowp,
                          float* __restrict__ out) {
    int r = blockIdx.x;
    int tid = threadIdx.x;   // 128 threads, 4 c's each
    float ce = rowp[r].z;
    float Ms[SPLITS], Ls[SPLITS];
    float M = -1e30f;
#pragma unroll
    for (int s = 0; s < SPLITS; ++s) {
        Ms[s] = pM[r * SPLITS + s];
        Ls[s] = pL[r * SPLITS + s];
        M = fmaxf(M, Ms[s]);
    }
    float es[SPLITS], L = 0.f;
#pragma unroll
    for (int s = 0; s < SPLITS; ++s) { es[s] = exp2f((Ms[s] - M) * ce); L += Ls[s] * es[s]; }
    float invL = 1.0f / L;
    f32x4 acc = (f32x4){0.f, 0.f, 0.f, 0.f};
#pragma unroll
    for (int s = 0; s < SPLITS; ++s) {
        f32x4 v = *(const f32x4*)(pO + ((size_t)r * SPLITS + s) * C_DIM + tid * 4);
        acc += v * es[s];
    }
    acc *= invL;
    *(f32x4*)(out + (size_t)r * C_DIM + tid * 4) = acc;
}

// ======================= launch =======================
extern "C" void kernel_launch(void* const* d_in, const int* in_sizes, int n_in,
                              void* d_out, int out_size, void* d_ws, size_t ws_size,
                              hipStream_t stream) {
    const float* x = (const float*)d_in[0];
    const int* t = (const int*)d_in[1];
    const float* A = (const float*)d_in[2];
    const float* bar_alpha = (const float*)d_in[3];
    float* out = (float*)d_out;
    char* ws = (char*)d_ws;
    if (ws_size < WS_NEED) return;

    char* imgA = ws + OFF_IMGA;
    char* imgC = ws + OFF_IMGC;
    unsigned short* Xh = (unsigned short*)(ws + OFF_XH);
    unsigned short* Xl = (unsigned short*)(ws + OFF_XL);
    float* Asq = (float*)(ws + OFF_ASQ);
    float4* rowp = (float4*)(ws + OFF_ROWP);
    float* pO = (float*)(ws + OFF_PO);
    float* pM = (float*)(ws + OFF_PM);
    float* pL = (float*)(ws + OFF_PL);

    (void)hipFuncSetAttribute((const void*)k_fused,
                              hipFuncAttributeMaxDynamicSharedMemorySize, SM_TOT);

    k_rows<<<R_DIM / 256, 256, 0, stream>>>(t, bar_alpha, rowp);
    k_splitx<<<(R_DIM * C_DIM / 8) / 256, 256, 0, stream>>>(x, (us8*)Xh, (us8*)Xl);
    k_imgA<<<GTILES * 8, 256, 0, stream>>>(A, imgA);
    k_imgC<<<GTILES * 8, 256, 0, stream>>>(A, imgC);
    k_asq<<<K_DIM / 4, 256, 0, stream>>>(A, Asq);
    k_fused<<<(R_DIM / BM) * SPLITS, 512, SM_TOT, stream>>>(imgA, imgC, Xh, Xl,
                                                            Asq, rowp, pO, pM, pL);
    k_combine<<<R_DIM, 128, 0, stream>>>(pO, pM, pL, rowp, out);
}